// Round 1
// baseline (168.910 us; speedup 1.0000x reference)
//
#include <hip/hip_runtime.h>
#include <cstdint>

#define NPRI 33600
#define NGT  256
#define NCLS 80
#define KTOP 13
#define INF_F 1.0e8f
#define EPS_F 1e-7f
#define L10 3.3219280948873623f
#define SLC  4
#define SLEN (NPRI / SLC)          // 8400
#define SCN_T 512
#define NW8 (SCN_T / 64)
#define NIT  ((SLEN + SCN_T - 1) / SCN_T)   // 17, uniform padded trip count
#define CAPI 1536                  // per-slice iou values
#define CAPC 512                   // per-slice cost candidates
#define RFIX 5.5f                  // fixed collect radius (strides); Dmax typically ~4.7
#define PREP_BLKS ((NPRI + 255) / 256)
#define NEGINF __int_as_float(0xff800000)

typedef unsigned long long u64;

__device__ __forceinline__ int get_label(const void* p, int j, int is64) {
    if (is64) return (int)((const long long*)p)[j];
    return ((const int*)p)[j];
}

// ---------- wave helpers (reduce + broadcast) ----------
__device__ __forceinline__ float wave_max_bc_f32(float v) {
    #pragma unroll
    for (int off = 32; off > 0; off >>= 1) v = fmaxf(v, __shfl_down(v, off, 64));
    return __int_as_float(__builtin_amdgcn_readfirstlane(__float_as_int(v)));
}
__device__ __forceinline__ u64 wave_min_bc_u64(u64 v) {
    #pragma unroll
    for (int off = 32; off > 0; off >>= 1) { u64 o = __shfl_down(v, off, 64); v = (o < v) ? o : v; }
    unsigned lo = (unsigned)__builtin_amdgcn_readfirstlane((int)(v & 0xffffffffull));
    unsigned hi = (unsigned)__builtin_amdgcn_readfirstlane((int)(v >> 32));
    return (((u64)hi) << 32) | lo;
}
// f32 multiset per-wave top-13: ballot single-lane elimination preserves duplicates
template<int NSL>
__device__ __forceinline__ void wave_merge_max13_f32(float (&l)[NSL], float* dst, int lane) {
    int p = 0;
    for (int r = 0; r < KTOP; ++r) {
        float cur = NEGINF;
        #pragma unroll
        for (int s = 0; s < NSL; ++s) if (s == p) cur = l[NSL - 1 - s];
        float bm = wave_max_bc_f32(cur);
        u64 m = __ballot(cur == bm && bm != NEGINF);
        int first = __ffsll(m) - 1;
        if (lane == first) p++;
        if (lane == 0) dst[r] = bm;
    }
}
// u64 per-wave top-13 min (keys idx-distinct -> single match per round)
template<int NSL>
__device__ __forceinline__ void wave_merge_minN(u64 (&l)[NSL], u64* dst, int lane) {
    int p = 0;
    for (int r = 0; r < KTOP; ++r) {
        u64 cur = ~0ull;
        #pragma unroll
        for (int s = 0; s < NSL; ++s) if (s == p) cur = l[s];
        u64 bm = wave_min_bc_u64(cur);
        if (cur == bm && bm != ~0ull) p++;
        if (lane == 0) dst[r] = bm;
    }
}

// ---------- exact formulas (verbatim round-2: bit-identical selection) ----------
__device__ __forceinline__ float iou_exact(float4 pb, float areap, float gx1, float gy1,
                                           float gx2, float gy2, float areag) {
    float iw = fmaxf(fminf(pb.z, gx2) - fmaxf(pb.x, gx1), 0.0f);
    float ih = fmaxf(fminf(pb.w, gy2) - fmaxf(pb.y, gy1), 0.0f);
    float inter = iw * ih;
    return inter / fmaxf(areap + areag - inter, 1e-6f);
}
__device__ __forceinline__ float cost_exact(float4 p2, float gcx, float gcy,
                                            float l, float iou) {
    float dx = p2.x - gcx, dy = p2.y - gcy;
    float dist = sqrtf(dx * dx + dy * dy) / p2.z;
    float soft = exp2f((dist - 3.0f) * L10);
    float sig = 1.0f / (1.0f + expf(-l));
    float dd = iou - sig;
    float bce = fmaxf(l, 0.0f) - l * iou + log1pf(expf(-fabsf(l)));
    float iouc = -logf(iou + EPS_F) * 3.0f;
    return bce * (dd * dd) + iouc + soft;
}

// ---------- prep: detect int64 + init + valid mask + packed array ----------
__global__ __launch_bounds__(256) void k_prep(
        const float* __restrict__ priors, const float* __restrict__ gt,
        const void* labels, const float* __restrict__ pboxes,
        float4* __restrict__ pbp,
        int* count, int* firstgt, int* flag, int* slice_done) {
    __shared__ float4 gbox[NGT];
    __shared__ int    gpad[NGT];
    __shared__ int    bad;
    const int tid = threadIdx.x;
    const int b = blockIdx.x;
    if (b == 0 && tid == 0) bad = 0;
    if (b == 0) slice_done[tid] = 0;     // NGT == 256 == blockDim
    {
        float4 bx = ((const float4*)gt)[tid];
        gbox[tid] = bx;
        gpad[tid] = ((bx.x + bx.y + bx.z + bx.w) > 0.0f) ? 1 : 0;
    }
    __syncthreads();
    if (b == 0 && tid < 128) {
        long long v = ((const long long*)labels)[tid];   // first 1024B: in-bounds either layout
        if (v < 0 || v >= NCLS) atomicOr(&bad, 1);
    }
    int i = b * 256 + tid;
    if (i < NPRI) {
        count[i] = 0; firstgt[i] = NGT;
        float4 pr = ((const float4*)priors)[i];
        float px = pr.x, py = pr.y;
        int v = 0;
        for (int j = 0; j < NGT; ++j) {
            float4 bx = gbox[j];
            float m = fminf(fminf(px - bx.x, py - bx.y), fminf(bx.z - px, bx.w - py));
            if (m > 0.0f && gpad[j]) { v = 1; break; }
        }
        pbp[2 * i]     = ((const float4*)pboxes)[i];
        pbp[2 * i + 1] = make_float4(px, py, pr.z, v ? 1.0f : 0.0f);
    }
    if (b == 0) {
        __syncthreads();
        if (tid == 0) *flag = bad ? 0 : 1;   // 1 => int64 layout
    }
}

// ---------- single-pass sliced scan; fused per-GT merge on last-finishing slice ----------
__global__ __launch_bounds__(SCN_T) void k_scan(
        const float* __restrict__ scores,
        const float4* __restrict__ pbp,
        const float* __restrict__ gt, const void* labels, const int* flag,
        float* __restrict__ part_iou, u64* __restrict__ part_cost,
        int* count, int* firstgt, int* slice_done) {
    const int tid = threadIdx.x, lane = tid & 63, wid = tid >> 6;
    const int j = blockIdx.x, slice = blockIdx.y;
    const int base = slice * SLEN;
    const int lim = base + SLEN;
    const int is64 = *flag;

    const float4 gb = ((const float4*)gt)[j];
    const float gx1 = gb.x, gy1 = gb.y, gx2 = gb.z, gy2 = gb.w;
    const float areag = (gx2 - gx1) * (gy2 - gy1);
    const float gcx = (gx1 + gx2) * 0.5f, gcy = (gy1 + gy2) * 0.5f;
    const int lab = get_label(labels, j, is64);

    __shared__ int s_ni, s_nc, s_mode, s_last;
    __shared__ float s_dmax;
    __shared__ float liou[CAPI];
    __shared__ int lcost[CAPC];
    __shared__ float wiof[NW8 * KTOP];   // fI fallback only
    __shared__ u64 wco[NW8 * KTOP];      // mode-2 fallback only
    __shared__ u64 csel[KTOP];
    if (tid == 0) { s_ni = 0; s_nc = 0; }
    __syncthreads();

    // ---- single pass, uniform 17-iter trip, 2-deep prefetch, wave-agg appends ----
    {
        const int i0 = base + tid;               // always < lim (SLEN > SCN_T)
        int ia1 = i0 + SCN_T; ia1 = (ia1 < lim) ? ia1 : i0;   // clamped, in-bounds
        float4 pb_c = pbp[2 * i0],  p2_c = pbp[2 * i0 + 1];
        float4 pb_n = pbp[2 * ia1], p2_n = pbp[2 * ia1 + 1];
        for (int it = 0; it < NIT; ++it) {
            int i = i0 + it * SCN_T;
            int ipre = i + 2 * SCN_T;
            int ic = (ipre < lim) ? ipre : i0;   // clamped prefetch address (always valid)
            float4 pb_p = pbp[2 * ic];
            float4 p2_p = pbp[2 * ic + 1];       // two loads in flight during ballots

            bool inb = (i < lim);
            float iou = 0.0f;
            bool pc = false;
            if (inb) {
                float areap = (pb_c.z - pb_c.x) * (pb_c.w - pb_c.y);
                float iw = fmaxf(fminf(pb_c.z, gx2) - fmaxf(pb_c.x, gx1), 0.0f);
                float ih = fmaxf(fminf(pb_c.w, gy2) - fmaxf(pb_c.y, gy1), 0.0f);
                float inter = iw * ih;
                iou = inter / fmaxf(areap + areag - inter, 1e-6f);   // exact
                if (p2_c.w != 0.0f) {
                    float dx = p2_c.x - gcx, dy = p2_c.y - gcy;
                    float rad = p2_c.z * RFIX;
                    pc = (dx * dx + dy * dy <= rad * rad * (1.0f + 1e-5f));
                }
            }
            bool pi = inb && (iou > 0.0f);
            u64 mi = __ballot(pi);
            if (mi) {
                int lead = __ffsll(mi) - 1;
                int cnt = __popcll(mi);
                int bs = 0;
                if (lane == lead) bs = atomicAdd(&s_ni, cnt);
                bs = __shfl(bs, lead, 64);
                if (pi) {
                    int p = bs + __popcll(mi & ((1ull << lane) - 1ull));
                    if (p < CAPI) liou[p] = iou;
                }
            }
            u64 mc = __ballot(pc);
            if (mc) {
                int lead = __ffsll(mc) - 1;
                int cnt = __popcll(mc);
                int bs = 0;
                if (lane == lead) bs = atomicAdd(&s_nc, cnt);
                bs = __shfl(bs, lead, 64);
                if (pc) {
                    int p = bs + __popcll(mc & ((1ull << lane) - 1ull));
                    if (p < CAPC) lcost[p] = i;
                }
            }
            pb_c = pb_n; p2_c = p2_n;
            pb_n = pb_p; p2_n = p2_p;
        }
    }
    __syncthreads();
    const int ni = s_ni, nc = s_nc;
    const int ncc = (nc < CAPC) ? nc : CAPC;
    const bool fI = (ni > CAPI);

    // ---- parallel single-wave merges: wave 0 = cost, wave 1 = iou ----
    if (wid == 0) {
        u64 lf[KTOP];
        #pragma unroll
        for (int s = 0; s < KTOP; ++s) lf[s] = ~0ull;
        for (int k = lane; k < ncc; k += 64) {   // <=8 per lane; 13-deep list complete
            int i = lcost[k];
            float4 pb = pbp[2 * i];
            float4 p2 = pbp[2 * i + 1];
            float areap = (pb.z - pb.x) * (pb.w - pb.y);
            float iou = iou_exact(pb, areap, gx1, gy1, gx2, gy2, areag);
            float ec = cost_exact(p2, gcx, gcy, scores[(size_t)i * NCLS + lab], iou);
            u64 ck = (((u64)__float_as_uint(ec)) << 32) | (unsigned)i;
            if (ck < lf[KTOP - 1]) {
                lf[KTOP - 1] = ck;
                #pragma unroll
                for (int s = KTOP - 1; s > 0; --s)
                    if (lf[s] < lf[s - 1]) { u64 t = lf[s]; lf[s] = lf[s - 1]; lf[s - 1] = t; }
            }
        }
        wave_merge_minN<KTOP>(lf, csel, lane);
        if (lane == 0) {
            u64 tk = csel[KTOP - 1];
            int mode; float dmax = 0.0f;
            if (tk == ~0ull) mode = 2;               // <13 candidates in RFIX ball
            else {
                float tau = __uint_as_float((unsigned)(tk >> 32));
                if (!(tau < 9.0e7f)) mode = 2;       // INF-ambiguity zone
                else {
                    dmax = 3.0f + __log2f(tau + 1e-5f) * (1.0f / L10) + 4e-3f;
                    mode = (dmax > RFIX || nc > CAPC) ? 1 : 0;
                }
            }
            s_mode = mode; s_dmax = dmax;
        }
    } else if (wid == 1 && !fI) {
        float lf[KTOP];
        #pragma unroll
        for (int s = 0; s < KTOP; ++s) lf[s] = NEGINF;
        int nn = (ni < CAPI) ? ni : CAPI;
        for (int k = lane; k < nn; k += 64) {    // <=24 per lane; 13-deep retains any lane's top-13
            float v = liou[k];
            if (v > lf[0]) {
                lf[0] = v;
                #pragma unroll
                for (int s = 0; s < KTOP - 1; ++s)
                    if (lf[s] > lf[s + 1]) { float t = lf[s]; lf[s] = lf[s + 1]; lf[s + 1] = t; }
            }
        }
        wave_merge_max13_f32<KTOP>(lf, part_iou + ((size_t)j * SLC + slice) * KTOP, lane);
    }
    __syncthreads();

    if (fI) {   // rare: iou list overflowed -> exact full-slice scan (two-stage merge)
        float lf[KTOP];
        #pragma unroll
        for (int s = 0; s < KTOP; ++s) lf[s] = NEGINF;
        for (int i = base + tid; i < lim; i += SCN_T) {
            float4 pb = pbp[2 * i];
            float areap = (pb.z - pb.x) * (pb.w - pb.y);
            float iou = iou_exact(pb, areap, gx1, gy1, gx2, gy2, areag);
            if (iou > lf[0]) {
                lf[0] = iou;
                #pragma unroll
                for (int s = 0; s < KTOP - 1; ++s)
                    if (lf[s] > lf[s + 1]) { float t = lf[s]; lf[s] = lf[s + 1]; lf[s + 1] = t; }
            }
        }
        wave_merge_max13_f32<KTOP>(lf, &wiof[wid * KTOP], lane);
        __syncthreads();
        if (wid == 0) {
            float* dpi = part_iou + ((size_t)j * SLC + slice) * KTOP;
            int p = 0;
            for (int r = 0; r < KTOP; ++r) {
                float cur = (lane < NW8 && p < KTOP) ? wiof[lane * KTOP + p] : NEGINF;
                float bm = wave_max_bc_f32(cur);
                u64 m = __ballot(cur == bm && bm != NEGINF);
                int first = __ffsll(m) - 1;
                if (lane == first) p++;
                if (lane == 0) dpi[r] = bm;
            }
        }
        __syncthreads();
    }

    int mode = s_mode;
    if (mode == 1) {   // re-collect at the sound radius Dmax' (rare)
        const float dmax = s_dmax;
        if (tid == 0) s_nc = 0;
        __syncthreads();
        for (int i = base + tid; i < lim; i += SCN_T) {
            float4 p2 = pbp[2 * i + 1];
            if (p2.w != 0.0f) {
                float dx = p2.x - gcx, dy = p2.y - gcy;
                float rad = p2.z * dmax;
                if (dx * dx + dy * dy <= rad * rad * (1.0f + 1e-5f)) {
                    int p = atomicAdd(&s_nc, 1);
                    if (p < CAPC) lcost[p] = i;
                }
            }
        }
        __syncthreads();
        int nc2 = s_nc;
        if (nc2 <= CAPC) {
            if (wid == 0) {
                u64 lf[KTOP];
                #pragma unroll
                for (int s = 0; s < KTOP; ++s) lf[s] = ~0ull;
                for (int k = lane; k < nc2; k += 64) {
                    int i = lcost[k];
                    float4 pb = pbp[2 * i];
                    float4 p2 = pbp[2 * i + 1];
                    float areap = (pb.z - pb.x) * (pb.w - pb.y);
                    float iou = iou_exact(pb, areap, gx1, gy1, gx2, gy2, areag);
                    float ec = cost_exact(p2, gcx, gcy, scores[(size_t)i * NCLS + lab], iou);
                    u64 ck = (((u64)__float_as_uint(ec)) << 32) | (unsigned)i;
                    if (ck < lf[KTOP - 1]) {
                        lf[KTOP - 1] = ck;
                        #pragma unroll
                        for (int s = KTOP - 1; s > 0; --s)
                            if (lf[s] < lf[s - 1]) { u64 t = lf[s]; lf[s] = lf[s - 1]; lf[s - 1] = t; }
                    }
                }
                wave_merge_minN<KTOP>(lf, csel, lane);
            }
        } else {
            mode = 2;   // uniform (s_nc shared)
        }
        __syncthreads();
    }
    if (mode == 2) {   // exact full slice scan (round-2 semantics; correctness net)
        u64 lf[KTOP];
        #pragma unroll
        for (int s = 0; s < KTOP; ++s) lf[s] = ~0ull;
        for (int i = base + tid; i < lim; i += SCN_T) {
            float4 pb = pbp[2 * i];
            float4 p2 = pbp[2 * i + 1];
            float areap = (pb.z - pb.x) * (pb.w - pb.y);
            float iou = iou_exact(pb, areap, gx1, gy1, gx2, gy2, areag);
            float ec = INF_F;
            if (p2.w != 0.0f) ec = cost_exact(p2, gcx, gcy, scores[(size_t)i * NCLS + lab], iou);
            u64 k2 = (((u64)__float_as_uint(ec)) << 32) | (unsigned)i;
            if (k2 < lf[KTOP - 1]) {
                lf[KTOP - 1] = k2;
                #pragma unroll
                for (int s = KTOP - 1; s > 0; --s)
                    if (lf[s] < lf[s - 1]) { u64 t = lf[s]; lf[s] = lf[s - 1]; lf[s - 1] = t; }
            }
        }
        wave_merge_minN<KTOP>(lf, &wco[wid * KTOP], lane);
        __syncthreads();
        if (wid == 0) {
            int p = 0;
            for (int r = 0; r < KTOP; ++r) {
                u64 cur = (lane < NW8 && p < KTOP) ? wco[lane * KTOP + p] : ~0ull;
                u64 bm = wave_min_bc_u64(cur);
                if (cur == bm && bm != ~0ull) p++;
                if (lane == 0) csel[r] = bm;
            }
        }
        __syncthreads();
    }
    if (tid < KTOP) {
        u64* dpc = part_cost + ((size_t)j * SLC + slice) * KTOP;
        dpc[tid] = csel[tid];
    }

    // ---- fused per-GT merge: last-finishing slice block merges all SLC slices ----
    __syncthreads();                         // drain this block's part writes (vmcnt0 before barrier)
    if (tid == 0) {
        __threadfence();                     // release: L2 writeback so other XCDs see our parts
        s_last = (atomicAdd(&slice_done[j], 1) == SLC - 1) ? 1 : 0;
    }
    __syncthreads();
    if (s_last && wid == 0) {
        __threadfence();                     // acquire: invalidate before reading peer parts
        const int l = lane;
        float vi = (l < SLC * KTOP) ? part_iou[(size_t)j * SLC * KTOP + l] : NEGINF;
        float tsum = 0.0f;
        for (int r = 0; r < KTOP; ++r) {
            float bm = wave_max_bc_f32(vi);
            u64 mmask = __ballot(vi == bm && bm != NEGINF);
            int first = __ffsll(mmask) - 1;
            if (l == first) vi = NEGINF;
            tsum += (bm == NEGINF) ? 0.0f : bm;   // descending-order sum (missing = 0, as ref)
        }
        int ks = (int)tsum;
        if (ks < 1) ks = 1;
        u64 kc = (l < SLC * KTOP) ? part_cost[(size_t)j * SLC * KTOP + l] : ~0ull;
        u64 mine = ~0ull;
        for (int r = 0; r < KTOP; ++r) {
            u64 bm = wave_min_bc_u64(kc);
            if (kc == bm && bm != ~0ull) kc = ~0ull;
            if (l == r) mine = bm;
        }
        if (l < KTOP && l < ks && mine != ~0ull) {
            int idx = (int)(unsigned)(mine & 0xFFFFFFFFull);
            atomicAdd(&count[idx], 1);
            atomicMin(&firstgt[idx], j);
        }
    }
}

// ---------- per-prior finalize; multi-matched priors resolved in-block ----------
__global__ __launch_bounds__(256) void k_assign(
        const float* __restrict__ scores,
        const float4* __restrict__ pbp, const float* __restrict__ gt,
        const void* labels, const int* flag,
        const int* __restrict__ count, const int* __restrict__ firstgt,
        float* __restrict__ out) {
    __shared__ float4 gbox[NGT];
    __shared__ int glab[NGT];
    __shared__ float gcxs[NGT], gcys[NGT], gareas[NGT];
    __shared__ int s_nm;
    __shared__ int s_mlist[256];
    __shared__ u64 red4[4];
    const int tid = threadIdx.x;
    const int is64 = *flag;
    {
        float4 b = ((const float4*)gt)[tid];
        gbox[tid] = b;
        glab[tid] = get_label(labels, tid, is64);
        gcxs[tid] = (b.x + b.z) * 0.5f;
        gcys[tid] = (b.y + b.w) * 0.5f;
        gareas[tid] = (b.z - b.x) * (b.w - b.y);
    }
    if (tid == 0) s_nm = 0;
    __syncthreads();
    const int i = blockIdx.x * 256 + tid;
    const bool act = (i < NPRI);
    if (act) {
        float4 p2 = pbp[2 * i + 1];
        int v = (p2.w != 0.0f) ? 1 : 0;
        int c = count[i];
        float o0 = 0.0f, o1 = -INF_F, o2 = -1.0f;
        if (v && c == 1) {
            int j = firstgt[i];
            float4 pb = pbp[2 * i];
            float areap = (pb.z - pb.x) * (pb.w - pb.y);
            float4 g = gbox[j];
            float iw = fmaxf(fminf(pb.z, g.z) - fmaxf(pb.x, g.x), 0.0f);
            float ih = fmaxf(fminf(pb.w, g.w) - fmaxf(pb.y, g.y), 0.0f);
            float inter = iw * ih;
            float iou = inter / fmaxf(areap + gareas[j] - inter, 1e-6f);
            o0 = (float)(j + 1); o1 = iou; o2 = (float)glab[j];
        } else if (v && c > 1) {
            int p = atomicAdd(&s_nm, 1);
            s_mlist[p] = i;
        }
        out[i] = o0;
        out[NPRI + i] = o1;
        out[2 * NPRI + i] = o2;
    }
    __syncthreads();
    // ---- in-block multi resolution: one GT per thread, block argmin per prior ----
    const int nm = s_nm;
    const int j = tid;
    for (int m = 0; m < nm; ++m) {
        const int ii = s_mlist[m];
        float4 pb = pbp[2 * ii];
        float4 p2 = pbp[2 * ii + 1];
        float areap = (pb.z - pb.x) * (pb.w - pb.y);

        float4 g = gbox[j];
        float iw = fmaxf(fminf(pb.z, g.z) - fmaxf(pb.x, g.x), 0.0f);
        float ih = fmaxf(fminf(pb.w, g.w) - fmaxf(pb.y, g.y), 0.0f);
        float inter = iw * ih;
        float iou = inter / fmaxf(areap + gareas[j] - inter, 1e-6f);
        float dx = p2.x - gcxs[j], dy = p2.y - gcys[j];
        float dist = sqrtf(dx * dx + dy * dy) / p2.z;
        float soft = exp2f((dist - 3.0f) * L10);
        float l = scores[(size_t)ii * NCLS + glab[j]];
        float sig = 1.0f / (1.0f + expf(-l));
        float dd = iou - sig;
        float bce = fmaxf(l, 0.0f) - l * iou + log1pf(expf(-fabsf(l)));
        float cost = bce * (dd * dd) + (-logf(iou + EPS_F) * 3.0f) + soft;

        u64 key = (((u64)__float_as_uint(cost)) << 32) | (unsigned)j;
        u64 v = key;
        #pragma unroll
        for (int off = 32; off > 0; off >>= 1) {
            u64 o = __shfl_down(v, off, 64);
            v = (o < v) ? o : v;
        }
        if ((tid & 63) == 0) red4[tid >> 6] = v;
        __syncthreads();
        u64 best = red4[0];
        #pragma unroll
        for (int q = 1; q < 4; ++q) best = (red4[q] < best) ? red4[q] : best;
        if (key == best) {
            out[ii] = (float)(j + 1);
            out[NPRI + ii] = iou;
            out[2 * NPRI + ii] = (float)glab[j];
        }
        __syncthreads();
    }
}

extern "C" void kernel_launch(void* const* d_in, const int* in_sizes, int n_in,
                              void* d_out, int out_size, void* d_ws, size_t ws_size,
                              hipStream_t stream) {
    const float* scores = (const float*)d_in[0];
    const float* priors = (const float*)d_in[1];
    const float* pboxes = (const float*)d_in[2];
    const float* gt     = (const float*)d_in[3];
    const void*  labels = d_in[4];
    float* out = (float*)d_out;

    char* ws = (char*)d_ws;
    size_t off = 0;
    auto alloc = [&](size_t bytes) { size_t o = off; off = (off + bytes + 255) & ~(size_t)255; return o; };
    int*    flag      = (int*)(ws + alloc(4));
    int*    slice_done= (int*)(ws + alloc((size_t)NGT * 4));
    int*    count     = (int*)(ws + alloc((size_t)NPRI * 4));
    int*    firstgt   = (int*)(ws + alloc((size_t)NPRI * 4));
    float*  part_iou  = (float*)(ws + alloc((size_t)NGT * SLC * KTOP * 4));
    u64*    part_cost = (u64*)(ws + alloc((size_t)NGT * SLC * KTOP * 8));
    float4* pbp       = (float4*)(ws + alloc((size_t)NPRI * 32));
    (void)ws_size;

    hipLaunchKernelGGL(k_prep, dim3(PREP_BLKS), dim3(256), 0, stream,
                       priors, gt, labels, pboxes, pbp, count, firstgt, flag, slice_done);
    hipLaunchKernelGGL(k_scan, dim3(NGT, SLC), dim3(SCN_T), 0, stream,
                       scores, pbp, gt, labels, flag, part_iou, part_cost,
                       count, firstgt, slice_done);
    hipLaunchKernelGGL(k_assign, dim3((NPRI + 255) / 256), dim3(256), 0, stream,
                       scores, pbp, gt, labels, flag, count, firstgt, out);
}

// Round 2
// 149.467 us; speedup vs baseline: 1.1301x; 1.1301x over previous
//
#include <hip/hip_runtime.h>
#include <cstdint>

#define NPRI 33600
#define NGT  256
#define NCLS 80
#define KTOP 13
#define INF_F 1.0e8f
#define EPS_F 1e-7f
#define L10 3.3219280948873623f
#define SLC  4
#define SLEN (NPRI / SLC)          // 8400
#define SCN_T 512
#define NW8 (SCN_T / 64)
#define NIT  ((SLEN + SCN_T - 1) / SCN_T)   // 17, uniform padded trip count
#define CAPI 1536                  // per-slice iou values
#define CAPC 512                   // per-slice cost candidates
#define RFIX 5.5f                  // fixed collect radius (strides); Dmax typically ~4.7
#define PREP_BLKS ((NPRI + 255) / 256)
#define NEGINF __int_as_float(0xff800000)

typedef unsigned long long u64;

__device__ __forceinline__ int get_label(const void* p, int j, int is64) {
    if (is64) return (int)((const long long*)p)[j];
    return ((const int*)p)[j];
}

// ---------- agent-coherent (cross-XCD) scalar access: sc1 ops, NO L2 writeback ----------
__device__ __forceinline__ void st_agent_f32(float* p, float v) {
    __hip_atomic_store(p, v, __ATOMIC_RELAXED, __HIP_MEMORY_SCOPE_AGENT);
}
__device__ __forceinline__ void st_agent_u64(u64* p, u64 v) {
    __hip_atomic_store(p, v, __ATOMIC_RELAXED, __HIP_MEMORY_SCOPE_AGENT);
}
__device__ __forceinline__ float ld_agent_f32(const float* p) {
    return __hip_atomic_load(p, __ATOMIC_RELAXED, __HIP_MEMORY_SCOPE_AGENT);
}
__device__ __forceinline__ u64 ld_agent_u64(const u64* p) {
    return __hip_atomic_load(p, __ATOMIC_RELAXED, __HIP_MEMORY_SCOPE_AGENT);
}

// ---------- wave helpers (reduce + broadcast) ----------
__device__ __forceinline__ float wave_max_bc_f32(float v) {
    #pragma unroll
    for (int off = 32; off > 0; off >>= 1) v = fmaxf(v, __shfl_down(v, off, 64));
    return __int_as_float(__builtin_amdgcn_readfirstlane(__float_as_int(v)));
}
__device__ __forceinline__ u64 wave_min_bc_u64(u64 v) {
    #pragma unroll
    for (int off = 32; off > 0; off >>= 1) { u64 o = __shfl_down(v, off, 64); v = (o < v) ? o : v; }
    unsigned lo = (unsigned)__builtin_amdgcn_readfirstlane((int)(v & 0xffffffffull));
    unsigned hi = (unsigned)__builtin_amdgcn_readfirstlane((int)(v >> 32));
    return (((u64)hi) << 32) | lo;
}
// f32 multiset per-wave top-13: ballot single-lane elimination preserves duplicates
// AGENT=true -> destination is global memory that another XCD's block will read mid-kernel
template<int NSL, bool AGENT>
__device__ __forceinline__ void wave_merge_max13_f32(float (&l)[NSL], float* dst, int lane) {
    int p = 0;
    for (int r = 0; r < KTOP; ++r) {
        float cur = NEGINF;
        #pragma unroll
        for (int s = 0; s < NSL; ++s) if (s == p) cur = l[NSL - 1 - s];
        float bm = wave_max_bc_f32(cur);
        u64 m = __ballot(cur == bm && bm != NEGINF);
        int first = __ffsll(m) - 1;
        if (lane == first) p++;
        if (lane == 0) {
            if (AGENT) st_agent_f32(dst + r, bm);
            else dst[r] = bm;
        }
    }
}
// u64 per-wave top-13 min (keys idx-distinct -> single match per round)
template<int NSL>
__device__ __forceinline__ void wave_merge_minN(u64 (&l)[NSL], u64* dst, int lane) {
    int p = 0;
    for (int r = 0; r < KTOP; ++r) {
        u64 cur = ~0ull;
        #pragma unroll
        for (int s = 0; s < NSL; ++s) if (s == p) cur = l[s];
        u64 bm = wave_min_bc_u64(cur);
        if (cur == bm && bm != ~0ull) p++;
        if (lane == 0) dst[r] = bm;
    }
}

// ---------- exact formulas (verbatim round-2: bit-identical selection) ----------
__device__ __forceinline__ float iou_exact(float4 pb, float areap, float gx1, float gy1,
                                           float gx2, float gy2, float areag) {
    float iw = fmaxf(fminf(pb.z, gx2) - fmaxf(pb.x, gx1), 0.0f);
    float ih = fmaxf(fminf(pb.w, gy2) - fmaxf(pb.y, gy1), 0.0f);
    float inter = iw * ih;
    return inter / fmaxf(areap + areag - inter, 1e-6f);
}
__device__ __forceinline__ float cost_exact(float4 p2, float gcx, float gcy,
                                            float l, float iou) {
    float dx = p2.x - gcx, dy = p2.y - gcy;
    float dist = sqrtf(dx * dx + dy * dy) / p2.z;
    float soft = exp2f((dist - 3.0f) * L10);
    float sig = 1.0f / (1.0f + expf(-l));
    float dd = iou - sig;
    float bce = fmaxf(l, 0.0f) - l * iou + log1pf(expf(-fabsf(l)));
    float iouc = -logf(iou + EPS_F) * 3.0f;
    return bce * (dd * dd) + iouc + soft;
}

// ---------- prep: detect int64 + init + valid mask + packed array ----------
__global__ __launch_bounds__(256) void k_prep(
        const float* __restrict__ priors, const float* __restrict__ gt,
        const void* labels, const float* __restrict__ pboxes,
        float4* __restrict__ pbp,
        int* count, int* firstgt, int* flag, int* slice_done) {
    __shared__ float4 gbox[NGT];
    __shared__ int    gpad[NGT];
    __shared__ int    bad;
    const int tid = threadIdx.x;
    const int b = blockIdx.x;
    if (b == 0 && tid == 0) bad = 0;
    if (b == 0) slice_done[tid] = 0;     // NGT == 256 == blockDim; inter-kernel flush makes visible
    {
        float4 bx = ((const float4*)gt)[tid];
        gbox[tid] = bx;
        gpad[tid] = ((bx.x + bx.y + bx.z + bx.w) > 0.0f) ? 1 : 0;
    }
    __syncthreads();
    if (b == 0 && tid < 128) {
        long long v = ((const long long*)labels)[tid];   // first 1024B: in-bounds either layout
        if (v < 0 || v >= NCLS) atomicOr(&bad, 1);
    }
    int i = b * 256 + tid;
    if (i < NPRI) {
        count[i] = 0; firstgt[i] = NGT;
        float4 pr = ((const float4*)priors)[i];
        float px = pr.x, py = pr.y;
        int v = 0;
        for (int j = 0; j < NGT; ++j) {
            float4 bx = gbox[j];
            float m = fminf(fminf(px - bx.x, py - bx.y), fminf(bx.z - px, bx.w - py));
            if (m > 0.0f && gpad[j]) { v = 1; break; }
        }
        pbp[2 * i]     = ((const float4*)pboxes)[i];
        pbp[2 * i + 1] = make_float4(px, py, pr.z, v ? 1.0f : 0.0f);
    }
    if (b == 0) {
        __syncthreads();
        if (tid == 0) *flag = bad ? 0 : 1;   // 1 => int64 layout
    }
}

// ---------- single-pass sliced scan; fused per-GT merge on last-finishing slice ----------
__global__ __launch_bounds__(SCN_T) void k_scan(
        const float* __restrict__ scores,
        const float4* __restrict__ pbp,
        const float* __restrict__ gt, const void* labels, const int* flag,
        float* __restrict__ part_iou, u64* __restrict__ part_cost,
        int* count, int* firstgt, int* slice_done) {
    const int tid = threadIdx.x, lane = tid & 63, wid = tid >> 6;
    const int j = blockIdx.x, slice = blockIdx.y;
    const int base = slice * SLEN;
    const int lim = base + SLEN;
    const int is64 = *flag;

    const float4 gb = ((const float4*)gt)[j];
    const float gx1 = gb.x, gy1 = gb.y, gx2 = gb.z, gy2 = gb.w;
    const float areag = (gx2 - gx1) * (gy2 - gy1);
    const float gcx = (gx1 + gx2) * 0.5f, gcy = (gy1 + gy2) * 0.5f;
    const int lab = get_label(labels, j, is64);

    __shared__ int s_ni, s_nc, s_mode, s_last;
    __shared__ float s_dmax;
    __shared__ float liou[CAPI];
    __shared__ int lcost[CAPC];
    __shared__ float wiof[NW8 * KTOP];   // fI fallback only
    __shared__ u64 wco[NW8 * KTOP];      // mode-2 fallback only
    __shared__ u64 csel[KTOP];
    if (tid == 0) { s_ni = 0; s_nc = 0; }
    __syncthreads();

    // ---- single pass, uniform 17-iter trip, 2-deep prefetch, wave-agg appends ----
    {
        const int i0 = base + tid;               // always < lim (SLEN > SCN_T)
        int ia1 = i0 + SCN_T; ia1 = (ia1 < lim) ? ia1 : i0;   // clamped, in-bounds
        float4 pb_c = pbp[2 * i0],  p2_c = pbp[2 * i0 + 1];
        float4 pb_n = pbp[2 * ia1], p2_n = pbp[2 * ia1 + 1];
        for (int it = 0; it < NIT; ++it) {
            int i = i0 + it * SCN_T;
            int ipre = i + 2 * SCN_T;
            int ic = (ipre < lim) ? ipre : i0;   // clamped prefetch address (always valid)
            float4 pb_p = pbp[2 * ic];
            float4 p2_p = pbp[2 * ic + 1];       // two loads in flight during ballots

            bool inb = (i < lim);
            float iou = 0.0f;
            bool pc = false;
            if (inb) {
                float areap = (pb_c.z - pb_c.x) * (pb_c.w - pb_c.y);
                float iw = fmaxf(fminf(pb_c.z, gx2) - fmaxf(pb_c.x, gx1), 0.0f);
                float ih = fmaxf(fminf(pb_c.w, gy2) - fmaxf(pb_c.y, gy1), 0.0f);
                float inter = iw * ih;
                iou = inter / fmaxf(areap + areag - inter, 1e-6f);   // exact
                if (p2_c.w != 0.0f) {
                    float dx = p2_c.x - gcx, dy = p2_c.y - gcy;
                    float rad = p2_c.z * RFIX;
                    pc = (dx * dx + dy * dy <= rad * rad * (1.0f + 1e-5f));
                }
            }
            bool pi = inb && (iou > 0.0f);
            u64 mi = __ballot(pi);
            if (mi) {
                int lead = __ffsll(mi) - 1;
                int cnt = __popcll(mi);
                int bs = 0;
                if (lane == lead) bs = atomicAdd(&s_ni, cnt);
                bs = __shfl(bs, lead, 64);
                if (pi) {
                    int p = bs + __popcll(mi & ((1ull << lane) - 1ull));
                    if (p < CAPI) liou[p] = iou;
                }
            }
            u64 mc = __ballot(pc);
            if (mc) {
                int lead = __ffsll(mc) - 1;
                int cnt = __popcll(mc);
                int bs = 0;
                if (lane == lead) bs = atomicAdd(&s_nc, cnt);
                bs = __shfl(bs, lead, 64);
                if (pc) {
                    int p = bs + __popcll(mc & ((1ull << lane) - 1ull));
                    if (p < CAPC) lcost[p] = i;
                }
            }
            pb_c = pb_n; p2_c = p2_n;
            pb_n = pb_p; p2_n = p2_p;
        }
    }
    __syncthreads();
    const int ni = s_ni, nc = s_nc;
    const int ncc = (nc < CAPC) ? nc : CAPC;
    const bool fI = (ni > CAPI);

    // ---- parallel single-wave merges: wave 0 = cost, wave 1 = iou ----
    if (wid == 0) {
        u64 lf[KTOP];
        #pragma unroll
        for (int s = 0; s < KTOP; ++s) lf[s] = ~0ull;
        for (int k = lane; k < ncc; k += 64) {   // <=8 per lane; 13-deep list complete
            int i = lcost[k];
            float4 pb = pbp[2 * i];
            float4 p2 = pbp[2 * i + 1];
            float areap = (pb.z - pb.x) * (pb.w - pb.y);
            float iou = iou_exact(pb, areap, gx1, gy1, gx2, gy2, areag);
            float ec = cost_exact(p2, gcx, gcy, scores[(size_t)i * NCLS + lab], iou);
            u64 ck = (((u64)__float_as_uint(ec)) << 32) | (unsigned)i;
            if (ck < lf[KTOP - 1]) {
                lf[KTOP - 1] = ck;
                #pragma unroll
                for (int s = KTOP - 1; s > 0; --s)
                    if (lf[s] < lf[s - 1]) { u64 t = lf[s]; lf[s] = lf[s - 1]; lf[s - 1] = t; }
            }
        }
        wave_merge_minN<KTOP>(lf, csel, lane);
        if (lane == 0) {
            u64 tk = csel[KTOP - 1];
            int mode; float dmax = 0.0f;
            if (tk == ~0ull) mode = 2;               // <13 candidates in RFIX ball
            else {
                float tau = __uint_as_float((unsigned)(tk >> 32));
                if (!(tau < 9.0e7f)) mode = 2;       // INF-ambiguity zone
                else {
                    dmax = 3.0f + __log2f(tau + 1e-5f) * (1.0f / L10) + 4e-3f;
                    mode = (dmax > RFIX || nc > CAPC) ? 1 : 0;
                }
            }
            s_mode = mode; s_dmax = dmax;
        }
    } else if (wid == 1 && !fI) {
        float lf[KTOP];
        #pragma unroll
        for (int s = 0; s < KTOP; ++s) lf[s] = NEGINF;
        int nn = (ni < CAPI) ? ni : CAPI;
        for (int k = lane; k < nn; k += 64) {    // <=24 per lane; 13-deep retains any lane's top-13
            float v = liou[k];
            if (v > lf[0]) {
                lf[0] = v;
                #pragma unroll
                for (int s = 0; s < KTOP - 1; ++s)
                    if (lf[s] > lf[s + 1]) { float t = lf[s]; lf[s] = lf[s + 1]; lf[s + 1] = t; }
            }
        }
        wave_merge_max13_f32<KTOP, true>(lf, part_iou + ((size_t)j * SLC + slice) * KTOP, lane);
    }
    __syncthreads();

    if (fI) {   // rare: iou list overflowed -> exact full-slice scan (two-stage merge)
        float lf[KTOP];
        #pragma unroll
        for (int s = 0; s < KTOP; ++s) lf[s] = NEGINF;
        for (int i = base + tid; i < lim; i += SCN_T) {
            float4 pb = pbp[2 * i];
            float areap = (pb.z - pb.x) * (pb.w - pb.y);
            float iou = iou_exact(pb, areap, gx1, gy1, gx2, gy2, areag);
            if (iou > lf[0]) {
                lf[0] = iou;
                #pragma unroll
                for (int s = 0; s < KTOP - 1; ++s)
                    if (lf[s] > lf[s + 1]) { float t = lf[s]; lf[s] = lf[s + 1]; lf[s + 1] = t; }
            }
        }
        wave_merge_max13_f32<KTOP, false>(lf, &wiof[wid * KTOP], lane);
        __syncthreads();
        if (wid == 0) {
            float* dpi = part_iou + ((size_t)j * SLC + slice) * KTOP;
            int p = 0;
            for (int r = 0; r < KTOP; ++r) {
                float cur = (lane < NW8 && p < KTOP) ? wiof[lane * KTOP + p] : NEGINF;
                float bm = wave_max_bc_f32(cur);
                u64 m = __ballot(cur == bm && bm != NEGINF);
                int first = __ffsll(m) - 1;
                if (lane == first) p++;
                if (lane == 0) st_agent_f32(dpi + r, bm);
            }
        }
        __syncthreads();
    }

    int mode = s_mode;
    if (mode == 1) {   // re-collect at the sound radius Dmax' (rare)
        const float dmax = s_dmax;
        if (tid == 0) s_nc = 0;
        __syncthreads();
        for (int i = base + tid; i < lim; i += SCN_T) {
            float4 p2 = pbp[2 * i + 1];
            if (p2.w != 0.0f) {
                float dx = p2.x - gcx, dy = p2.y - gcy;
                float rad = p2.z * dmax;
                if (dx * dx + dy * dy <= rad * rad * (1.0f + 1e-5f)) {
                    int p = atomicAdd(&s_nc, 1);
                    if (p < CAPC) lcost[p] = i;
                }
            }
        }
        __syncthreads();
        int nc2 = s_nc;
        if (nc2 <= CAPC) {
            if (wid == 0) {
                u64 lf[KTOP];
                #pragma unroll
                for (int s = 0; s < KTOP; ++s) lf[s] = ~0ull;
                for (int k = lane; k < nc2; k += 64) {
                    int i = lcost[k];
                    float4 pb = pbp[2 * i];
                    float4 p2 = pbp[2 * i + 1];
                    float areap = (pb.z - pb.x) * (pb.w - pb.y);
                    float iou = iou_exact(pb, areap, gx1, gy1, gx2, gy2, areag);
                    float ec = cost_exact(p2, gcx, gcy, scores[(size_t)i * NCLS + lab], iou);
                    u64 ck = (((u64)__float_as_uint(ec)) << 32) | (unsigned)i;
                    if (ck < lf[KTOP - 1]) {
                        lf[KTOP - 1] = ck;
                        #pragma unroll
                        for (int s = KTOP - 1; s > 0; --s)
                            if (lf[s] < lf[s - 1]) { u64 t = lf[s]; lf[s] = lf[s - 1]; lf[s - 1] = t; }
                    }
                }
                wave_merge_minN<KTOP>(lf, csel, lane);
            }
        } else {
            mode = 2;   // uniform (s_nc shared)
        }
        __syncthreads();
    }
    if (mode == 2) {   // exact full slice scan (round-2 semantics; correctness net)
        u64 lf[KTOP];
        #pragma unroll
        for (int s = 0; s < KTOP; ++s) lf[s] = ~0ull;
        for (int i = base + tid; i < lim; i += SCN_T) {
            float4 pb = pbp[2 * i];
            float4 p2 = pbp[2 * i + 1];
            float areap = (pb.z - pb.x) * (pb.w - pb.y);
            float iou = iou_exact(pb, areap, gx1, gy1, gx2, gy2, areag);
            float ec = INF_F;
            if (p2.w != 0.0f) ec = cost_exact(p2, gcx, gcy, scores[(size_t)i * NCLS + lab], iou);
            u64 k2 = (((u64)__float_as_uint(ec)) << 32) | (unsigned)i;
            if (k2 < lf[KTOP - 1]) {
                lf[KTOP - 1] = k2;
                #pragma unroll
                for (int s = KTOP - 1; s > 0; --s)
                    if (lf[s] < lf[s - 1]) { u64 t = lf[s]; lf[s] = lf[s - 1]; lf[s - 1] = t; }
            }
        }
        wave_merge_minN<KTOP>(lf, &wco[wid * KTOP], lane);
        __syncthreads();
        if (wid == 0) {
            int p = 0;
            for (int r = 0; r < KTOP; ++r) {
                u64 cur = (lane < NW8 && p < KTOP) ? wco[lane * KTOP + p] : ~0ull;
                u64 bm = wave_min_bc_u64(cur);
                if (cur == bm && bm != ~0ull) p++;
                if (lane == 0) csel[r] = bm;
            }
        }
        __syncthreads();
    }
    if (tid < KTOP) {
        u64* dpc = part_cost + ((size_t)j * SLC + slice) * KTOP;
        st_agent_u64(dpc + tid, csel[tid]);
    }

    // ---- fused per-GT merge: last-finishing slice block merges all SLC slices ----
    // Protocol: all part stores above are sc1 (agent-coherent). __syncthreads drains
    // vmcnt(0) before its barrier, so they are globally visible BEFORE the flag bump.
    // NO __threadfence (= buffer_wbl2/inv full-L2 flush) anywhere — that was the
    // round-0->1 regression (+30us of L2 thrash in k_scan).
    asm volatile("s_waitcnt vmcnt(0)" ::: "memory");
    __syncthreads();
    if (tid == 0) s_last = (atomicAdd(&slice_done[j], 1) == SLC - 1) ? 1 : 0;
    __syncthreads();
    if (s_last && wid == 0) {
        const int l = lane;
        float vi = (l < SLC * KTOP) ? ld_agent_f32(part_iou + (size_t)j * SLC * KTOP + l) : NEGINF;
        float tsum = 0.0f;
        for (int r = 0; r < KTOP; ++r) {
            float bm = wave_max_bc_f32(vi);
            u64 mmask = __ballot(vi == bm && bm != NEGINF);
            int first = __ffsll(mmask) - 1;
            if (l == first) vi = NEGINF;
            tsum += (bm == NEGINF) ? 0.0f : bm;   // descending-order sum (missing = 0, as ref)
        }
        int ks = (int)tsum;
        if (ks < 1) ks = 1;
        u64 kc = (l < SLC * KTOP) ? ld_agent_u64(part_cost + (size_t)j * SLC * KTOP + l) : ~0ull;
        u64 mine = ~0ull;
        for (int r = 0; r < KTOP; ++r) {
            u64 bm = wave_min_bc_u64(kc);
            if (kc == bm && bm != ~0ull) kc = ~0ull;
            if (l == r) mine = bm;
        }
        if (l < KTOP && l < ks && mine != ~0ull) {
            int idx = (int)(unsigned)(mine & 0xFFFFFFFFull);
            atomicAdd(&count[idx], 1);
            atomicMin(&firstgt[idx], j);
        }
    }
}

// ---------- per-prior finalize; multi-matched priors resolved in-block ----------
__global__ __launch_bounds__(256) void k_assign(
        const float* __restrict__ scores,
        const float4* __restrict__ pbp, const float* __restrict__ gt,
        const void* labels, const int* flag,
        const int* __restrict__ count, const int* __restrict__ firstgt,
        float* __restrict__ out) {
    __shared__ float4 gbox[NGT];
    __shared__ int glab[NGT];
    __shared__ float gcxs[NGT], gcys[NGT], gareas[NGT];
    __shared__ int s_nm;
    __shared__ int s_mlist[256];
    __shared__ u64 red4[4];
    const int tid = threadIdx.x;
    const int is64 = *flag;
    {
        float4 b = ((const float4*)gt)[tid];
        gbox[tid] = b;
        glab[tid] = get_label(labels, tid, is64);
        gcxs[tid] = (b.x + b.z) * 0.5f;
        gcys[tid] = (b.y + b.w) * 0.5f;
        gareas[tid] = (b.z - b.x) * (b.w - b.y);
    }
    if (tid == 0) s_nm = 0;
    __syncthreads();
    const int i = blockIdx.x * 256 + tid;
    const bool act = (i < NPRI);
    if (act) {
        float4 p2 = pbp[2 * i + 1];
        int v = (p2.w != 0.0f) ? 1 : 0;
        int c = count[i];
        float o0 = 0.0f, o1 = -INF_F, o2 = -1.0f;
        if (v && c == 1) {
            int j = firstgt[i];
            float4 pb = pbp[2 * i];
            float areap = (pb.z - pb.x) * (pb.w - pb.y);
            float4 g = gbox[j];
            float iw = fmaxf(fminf(pb.z, g.z) - fmaxf(pb.x, g.x), 0.0f);
            float ih = fmaxf(fminf(pb.w, g.w) - fmaxf(pb.y, g.y), 0.0f);
            float inter = iw * ih;
            float iou = inter / fmaxf(areap + gareas[j] - inter, 1e-6f);
            o0 = (float)(j + 1); o1 = iou; o2 = (float)glab[j];
        } else if (v && c > 1) {
            int p = atomicAdd(&s_nm, 1);
            s_mlist[p] = i;
        }
        out[i] = o0;
        out[NPRI + i] = o1;
        out[2 * NPRI + i] = o2;
    }
    __syncthreads();
    // ---- in-block multi resolution: one GT per thread, block argmin per prior ----
    const int nm = s_nm;
    const int j = tid;
    for (int m = 0; m < nm; ++m) {
        const int ii = s_mlist[m];
        float4 pb = pbp[2 * ii];
        float4 p2 = pbp[2 * ii + 1];
        float areap = (pb.z - pb.x) * (pb.w - pb.y);

        float4 g = gbox[j];
        float iw = fmaxf(fminf(pb.z, g.z) - fmaxf(pb.x, g.x), 0.0f);
        float ih = fmaxf(fminf(pb.w, g.w) - fmaxf(pb.y, g.y), 0.0f);
        float inter = iw * ih;
        float iou = inter / fmaxf(areap + gareas[j] - inter, 1e-6f);
        float dx = p2.x - gcxs[j], dy = p2.y - gcys[j];
        float dist = sqrtf(dx * dx + dy * dy) / p2.z;
        float soft = exp2f((dist - 3.0f) * L10);
        float l = scores[(size_t)ii * NCLS + glab[j]];
        float sig = 1.0f / (1.0f + expf(-l));
        float dd = iou - sig;
        float bce = fmaxf(l, 0.0f) - l * iou + log1pf(expf(-fabsf(l)));
        float cost = bce * (dd * dd) + (-logf(iou + EPS_F) * 3.0f) + soft;

        u64 key = (((u64)__float_as_uint(cost)) << 32) | (unsigned)j;
        u64 v = key;
        #pragma unroll
        for (int off = 32; off > 0; off >>= 1) {
            u64 o = __shfl_down(v, off, 64);
            v = (o < v) ? o : v;
        }
        if ((tid & 63) == 0) red4[tid >> 6] = v;
        __syncthreads();
        u64 best = red4[0];
        #pragma unroll
        for (int q = 1; q < 4; ++q) best = (red4[q] < best) ? red4[q] : best;
        if (key == best) {
            out[ii] = (float)(j + 1);
            out[NPRI + ii] = iou;
            out[2 * NPRI + ii] = (float)glab[j];
        }
        __syncthreads();
    }
}

extern "C" void kernel_launch(void* const* d_in, const int* in_sizes, int n_in,
                              void* d_out, int out_size, void* d_ws, size_t ws_size,
                              hipStream_t stream) {
    const float* scores = (const float*)d_in[0];
    const float* priors = (const float*)d_in[1];
    const float* pboxes = (const float*)d_in[2];
    const float* gt     = (const float*)d_in[3];
    const void*  labels = d_in[4];
    float* out = (float*)d_out;

    char* ws = (char*)d_ws;
    size_t off = 0;
    auto alloc = [&](size_t bytes) { size_t o = off; off = (off + bytes + 255) & ~(size_t)255; return o; };
    int*    flag      = (int*)(ws + alloc(4));
    int*    slice_done= (int*)(ws + alloc((size_t)NGT * 4));
    int*    count     = (int*)(ws + alloc((size_t)NPRI * 4));
    int*    firstgt   = (int*)(ws + alloc((size_t)NPRI * 4));
    float*  part_iou  = (float*)(ws + alloc((size_t)NGT * SLC * KTOP * 4));
    u64*    part_cost = (u64*)(ws + alloc((size_t)NGT * SLC * KTOP * 8));
    float4* pbp       = (float4*)(ws + alloc((size_t)NPRI * 32));
    (void)ws_size;

    hipLaunchKernelGGL(k_prep, dim3(PREP_BLKS), dim3(256), 0, stream,
                       priors, gt, labels, pboxes, pbp, count, firstgt, flag, slice_done);
    hipLaunchKernelGGL(k_scan, dim3(NGT, SLC), dim3(SCN_T), 0, stream,
                       scores, pbp, gt, labels, flag, part_iou, part_cost,
                       count, firstgt, slice_done);
    hipLaunchKernelGGL(k_assign, dim3((NPRI + 255) / 256), dim3(256), 0, stream,
                       scores, pbp, gt, labels, flag, count, firstgt, out);
}

// Round 4
// 140.073 us; speedup vs baseline: 1.2059x; 1.0671x over previous
//
#include <hip/hip_runtime.h>
#include <cstdint>

#define NPRI 33600
#define NGT  256
#define NCLS 80
#define KTOP 13
#define INF_F 1.0e8f
#define EPS_F 1e-7f
#define L10 3.3219280948873623f
#define SCN_T 1024
#define NW   (SCN_T / 64)                   // 16 waves per block
#define NIT  ((NPRI + SCN_T - 1) / SCN_T)   // 33, uniform padded trip count
#define CAPI 4096                  // per-GT positive-iou values (full range)
#define CAPC 1024                  // per-GT cost candidates (full range)
#define RFIX 5.5f                  // fixed collect radius (strides); Dmax typically ~4.7
#define PREP_BLKS ((NPRI + 255) / 256)
#define NEGINF __int_as_float(0xff800000)

typedef unsigned long long u64;

__device__ __forceinline__ int get_label(const void* p, int j, int is64) {
    if (is64) return (int)((const long long*)p)[j];
    return ((const int*)p)[j];
}

// ---------- wave helpers (reduce + broadcast) ----------
__device__ __forceinline__ float wave_max_bc_f32(float v) {
    #pragma unroll
    for (int off = 32; off > 0; off >>= 1) v = fmaxf(v, __shfl_down(v, off, 64));
    return __int_as_float(__builtin_amdgcn_readfirstlane(__float_as_int(v)));
}
__device__ __forceinline__ u64 wave_min_bc_u64(u64 v) {
    #pragma unroll
    for (int off = 32; off > 0; off >>= 1) { u64 o = __shfl_down(v, off, 64); v = (o < v) ? o : v; }
    unsigned lo = (unsigned)__builtin_amdgcn_readfirstlane((int)(v & 0xffffffffull));
    unsigned hi = (unsigned)__builtin_amdgcn_readfirstlane((int)(v >> 32));
    return (((u64)hi) << 32) | lo;
}
// f32 multiset per-wave top-13: ballot single-lane elimination preserves duplicates
template<int NSL>
__device__ __forceinline__ void wave_merge_max13_f32(float (&l)[NSL], float* dst, int lane) {
    int p = 0;
    for (int r = 0; r < KTOP; ++r) {
        float cur = NEGINF;
        #pragma unroll
        for (int s = 0; s < NSL; ++s) if (s == p) cur = l[NSL - 1 - s];
        float bm = wave_max_bc_f32(cur);
        u64 m = __ballot(cur == bm && bm != NEGINF);
        int first = __ffsll(m) - 1;
        if (lane == first) p++;
        if (lane == 0) dst[r] = bm;
    }
}
// u64 per-wave top-13 min (keys idx-distinct -> single match per round)
template<int NSL>
__device__ __forceinline__ void wave_merge_minN(u64 (&l)[NSL], u64* dst, int lane) {
    int p = 0;
    for (int r = 0; r < KTOP; ++r) {
        u64 cur = ~0ull;
        #pragma unroll
        for (int s = 0; s < NSL; ++s) if (s == p) cur = l[s];
        u64 bm = wave_min_bc_u64(cur);
        if (cur == bm && bm != ~0ull) p++;
        if (lane == 0) dst[r] = bm;
    }
}

// ---------- exact formulas (verbatim: bit-identical selection) ----------
__device__ __forceinline__ float iou_exact(float4 pb, float areap, float gx1, float gy1,
                                           float gx2, float gy2, float areag) {
    float iw = fmaxf(fminf(pb.z, gx2) - fmaxf(pb.x, gx1), 0.0f);
    float ih = fmaxf(fminf(pb.w, gy2) - fmaxf(pb.y, gy1), 0.0f);
    float inter = iw * ih;
    return inter / fmaxf(areap + areag - inter, 1e-6f);
}
__device__ __forceinline__ float cost_exact(float4 p2, float gcx, float gcy,
                                            float l, float iou) {
    float dx = p2.x - gcx, dy = p2.y - gcy;
    float dist = sqrtf(dx * dx + dy * dy) / p2.z;
    float soft = exp2f((dist - 3.0f) * L10);
    float sig = 1.0f / (1.0f + expf(-l));
    float dd = iou - sig;
    float bce = fmaxf(l, 0.0f) - l * iou + log1pf(expf(-fabsf(l)));
    float iouc = -logf(iou + EPS_F) * 3.0f;
    return bce * (dd * dd) + iouc + soft;
}

// ---------- prep: detect int64 + init + valid mask + packed array ----------
__global__ __launch_bounds__(256) void k_prep(
        const float* __restrict__ priors, const float* __restrict__ gt,
        const void* labels, const float* __restrict__ pboxes,
        float4* __restrict__ pbp,
        int* count, int* firstgt, int* flag) {
    __shared__ float4 gbox[NGT];
    __shared__ int    gpad[NGT];
    __shared__ int    bad;
    const int tid = threadIdx.x;
    const int b = blockIdx.x;
    if (b == 0 && tid == 0) bad = 0;
    {
        float4 bx = ((const float4*)gt)[tid];
        gbox[tid] = bx;
        gpad[tid] = ((bx.x + bx.y + bx.z + bx.w) > 0.0f) ? 1 : 0;
    }
    __syncthreads();
    if (b == 0 && tid < 128) {
        long long v = ((const long long*)labels)[tid];   // first 1024B: in-bounds either layout
        if (v < 0 || v >= NCLS) atomicOr(&bad, 1);
    }
    int i = b * 256 + tid;
    if (i < NPRI) {
        count[i] = 0; firstgt[i] = NGT;
        float4 pr = ((const float4*)priors)[i];
        float px = pr.x, py = pr.y;
        int v = 0;
        for (int j = 0; j < NGT; ++j) {
            float4 bx = gbox[j];
            float m = fminf(fminf(px - bx.x, py - bx.y), fminf(bx.z - px, bx.w - py));
            if (m > 0.0f && gpad[j]) { v = 1; break; }
        }
        pbp[2 * i]     = ((const float4*)pboxes)[i];
        pbp[2 * i + 1] = make_float4(px, py, pr.z, v ? 1.0f : 0.0f);
    }
    if (b == 0) {
        __syncthreads();
        if (tid == 0) *flag = bad ? 0 : 1;   // 1 => int64 layout
    }
}

// ---------- one block per GT: full-range scan + complete merge + scatter ----------
// No slices, no cross-block protocol. Appends are rare -> plain divergent LDS
// atomics (no ballot-agg chains: those serial LDS-atomic+bpermute chains were
// the round-2 latency bottleneck at 36% occupancy).
__global__ __launch_bounds__(SCN_T) void k_scan(
        const float* __restrict__ scores,
        const float4* __restrict__ pbp,
        const float* __restrict__ gt, const void* labels, const int* flag,
        int* count, int* firstgt) {
    const int tid = threadIdx.x, lane = tid & 63, wid = tid >> 6;
    const int j = blockIdx.x;
    const int is64 = *flag;

    const float4 gb = ((const float4*)gt)[j];
    const float gx1 = gb.x, gy1 = gb.y, gx2 = gb.z, gy2 = gb.w;
    const float areag = (gx2 - gx1) * (gy2 - gy1);
    const float gcx = (gx1 + gx2) * 0.5f, gcy = (gy1 + gy2) * 0.5f;
    const int lab = get_label(labels, j, is64);

    __shared__ int s_ni, s_nc, s_mode;
    __shared__ float s_dmax;
    __shared__ float liou[CAPI];
    __shared__ int lcost[CAPC];
    __shared__ float wiof[(NW - 1) * KTOP];   // 15 partial iou lists (waves 1..15)
    __shared__ u64 wco[NW * KTOP];            // mode-2 fallback only
    __shared__ u64 csel[KTOP];
    __shared__ float s_iou13[KTOP];
    if (tid == 0) { s_ni = 0; s_nc = 0; }
    __syncthreads();

    // ---- single pass over all priors, uniform 33-iter trip, 2-deep prefetch ----
    {
        const int i0 = tid;                      // < NPRI
        const int ia1 = i0 + SCN_T;              // < NPRI (2048 < 33600)
        float4 pb_c = pbp[2 * i0],  p2_c = pbp[2 * i0 + 1];
        float4 pb_n = pbp[2 * ia1], p2_n = pbp[2 * ia1 + 1];
        for (int it = 0; it < NIT; ++it) {
            int i = i0 + it * SCN_T;
            int ipre = i + 2 * SCN_T;
            int ic = (ipre < NPRI) ? ipre : i0;  // clamped prefetch address (always valid)
            float4 pb_p = pbp[2 * ic];
            float4 p2_p = pbp[2 * ic + 1];       // two loads in flight during compute

            bool inb = (i < NPRI);
            float iou = 0.0f;
            bool pc = false;
            if (inb) {
                float areap = (pb_c.z - pb_c.x) * (pb_c.w - pb_c.y);
                float iw = fmaxf(fminf(pb_c.z, gx2) - fmaxf(pb_c.x, gx1), 0.0f);
                float ih = fmaxf(fminf(pb_c.w, gy2) - fmaxf(pb_c.y, gy1), 0.0f);
                float inter = iw * ih;
                iou = inter / fmaxf(areap + areag - inter, 1e-6f);   // exact
                if (p2_c.w != 0.0f) {
                    float dx = p2_c.x - gcx, dy = p2_c.y - gcy;
                    float rad = p2_c.z * RFIX;
                    pc = (dx * dx + dy * dy <= rad * rad * (1.0f + 1e-5f));
                }
            }
            // rare events -> plain divergent LDS atomics (no ballot-agg chains)
            if (inb && iou > 0.0f) {
                int p = atomicAdd(&s_ni, 1);
                if (p < CAPI) liou[p] = iou;
            }
            if (pc) {
                int p = atomicAdd(&s_nc, 1);
                if (p < CAPC) lcost[p] = i;
            }
            pb_c = pb_n; p2_c = p2_n;
            pb_n = pb_p; p2_n = p2_p;
        }
    }
    __syncthreads();
    const int ni = s_ni, nc = s_nc;
    const int ncc = (nc < CAPC) ? nc : CAPC;
    const bool fI = (ni > CAPI);

    // ---- phase 1: wave 0 = cost merge; waves 1..15 = iou partial merges ----
    if (wid == 0) {
        u64 lf[KTOP];
        #pragma unroll
        for (int s = 0; s < KTOP; ++s) lf[s] = ~0ull;
        for (int k = lane; k < ncc; k += 64) {   // <=16 per lane; 13-deep list complete
            int i = lcost[k];
            float4 pb = pbp[2 * i];
            float4 p2 = pbp[2 * i + 1];
            float areap = (pb.z - pb.x) * (pb.w - pb.y);
            float iou = iou_exact(pb, areap, gx1, gy1, gx2, gy2, areag);
            float ec = cost_exact(p2, gcx, gcy, scores[(size_t)i * NCLS + lab], iou);
            u64 ck = (((u64)__float_as_uint(ec)) << 32) | (unsigned)i;
            if (ck < lf[KTOP - 1]) {
                lf[KTOP - 1] = ck;
                #pragma unroll
                for (int s = KTOP - 1; s > 0; --s)
                    if (lf[s] < lf[s - 1]) { u64 t = lf[s]; lf[s] = lf[s - 1]; lf[s - 1] = t; }
            }
        }
        wave_merge_minN<KTOP>(lf, csel, lane);
        if (lane == 0) {
            u64 tk = csel[KTOP - 1];
            int mode; float dmax = 0.0f;
            if (tk == ~0ull) mode = 2;               // <13 candidates in RFIX ball
            else {
                float tau = __uint_as_float((unsigned)(tk >> 32));
                if (!(tau < 9.0e7f)) mode = 2;       // INF-ambiguity zone
                else {
                    dmax = 3.0f + __log2f(tau + 1e-5f) * (1.0f / L10) + 4e-3f;
                    mode = (dmax > RFIX || nc > CAPC) ? 1 : 0;
                }
            }
            s_mode = mode; s_dmax = dmax;
        }
    } else if (!fI) {
        float lf[KTOP];
        #pragma unroll
        for (int s = 0; s < KTOP; ++s) lf[s] = NEGINF;
        for (int k = (wid - 1) * 64 + lane; k < ni; k += 64 * (NW - 1)) {  // ~4-5 per lane
            float v = liou[k];
            if (v > lf[0]) {
                lf[0] = v;
                #pragma unroll
                for (int s = 0; s < KTOP - 1; ++s)
                    if (lf[s] > lf[s + 1]) { float t = lf[s]; lf[s] = lf[s + 1]; lf[s + 1] = t; }
            }
        }
        wave_merge_max13_f32<KTOP>(lf, &wiof[(wid - 1) * KTOP], lane);
    }
    __syncthreads();

    if (fI) {   // rare: iou list overflowed -> exact full rescan by waves 1..15
        if (wid > 0) {
            float lf[KTOP];
            #pragma unroll
            for (int s = 0; s < KTOP; ++s) lf[s] = NEGINF;
            for (int i = (wid - 1) * 64 + lane; i < NPRI; i += 64 * (NW - 1)) {
                float4 pb = pbp[2 * i];
                float areap = (pb.z - pb.x) * (pb.w - pb.y);
                float iou = iou_exact(pb, areap, gx1, gy1, gx2, gy2, areag);
                if (iou > 0.0f && iou > lf[0]) {
                    lf[0] = iou;
                    #pragma unroll
                    for (int s = 0; s < KTOP - 1; ++s)
                        if (lf[s] > lf[s + 1]) { float t = lf[s]; lf[s] = lf[s + 1]; lf[s + 1] = t; }
                }
            }
            wave_merge_max13_f32<KTOP>(lf, &wiof[(wid - 1) * KTOP], lane);
        }
        __syncthreads();
    }

    // ---- cross-merge the 15 iou lists -> s_iou13 (descending, multiset) ----
    if (wid == 0) {
        int p = 0;
        for (int r = 0; r < KTOP; ++r) {
            float cur = (lane < NW - 1 && p < KTOP) ? wiof[lane * KTOP + p] : NEGINF;
            float bm = wave_max_bc_f32(cur);
            u64 m = __ballot(cur == bm && bm != NEGINF);
            int first = __ffsll(m) - 1;
            if (lane == first) p++;
            if (lane == 0) s_iou13[r] = bm;
        }
    }

    int mode = s_mode;
    if (mode == 1) {   // re-collect at the sound radius Dmax' (rare)
        const float dmax = s_dmax;
        if (tid == 0) s_nc = 0;
        __syncthreads();
        for (int i = tid; i < NPRI; i += SCN_T) {
            float4 p2 = pbp[2 * i + 1];
            if (p2.w != 0.0f) {
                float dx = p2.x - gcx, dy = p2.y - gcy;
                float rad = p2.z * dmax;
                if (dx * dx + dy * dy <= rad * rad * (1.0f + 1e-5f)) {
                    int p = atomicAdd(&s_nc, 1);
                    if (p < CAPC) lcost[p] = i;
                }
            }
        }
        __syncthreads();
        int nc2 = s_nc;
        if (nc2 <= CAPC) {
            if (wid == 0) {
                u64 lf[KTOP];
                #pragma unroll
                for (int s = 0; s < KTOP; ++s) lf[s] = ~0ull;
                for (int k = lane; k < nc2; k += 64) {
                    int i = lcost[k];
                    float4 pb = pbp[2 * i];
                    float4 p2 = pbp[2 * i + 1];
                    float areap = (pb.z - pb.x) * (pb.w - pb.y);
                    float iou = iou_exact(pb, areap, gx1, gy1, gx2, gy2, areag);
                    float ec = cost_exact(p2, gcx, gcy, scores[(size_t)i * NCLS + lab], iou);
                    u64 ck = (((u64)__float_as_uint(ec)) << 32) | (unsigned)i;
                    if (ck < lf[KTOP - 1]) {
                        lf[KTOP - 1] = ck;
                        #pragma unroll
                        for (int s = KTOP - 1; s > 0; --s)
                            if (lf[s] < lf[s - 1]) { u64 t = lf[s]; lf[s] = lf[s - 1]; lf[s - 1] = t; }
                    }
                }
                wave_merge_minN<KTOP>(lf, csel, lane);
            }
        } else {
            mode = 2;   // uniform (s_nc shared)
        }
        __syncthreads();
    }
    if (mode == 2) {   // exact full scan (correctness net)
        u64 lf[KTOP];
        #pragma unroll
        for (int s = 0; s < KTOP; ++s) lf[s] = ~0ull;
        for (int i = tid; i < NPRI; i += SCN_T) {
            float4 pb = pbp[2 * i];
            float4 p2 = pbp[2 * i + 1];
            float areap = (pb.z - pb.x) * (pb.w - pb.y);
            float iou = iou_exact(pb, areap, gx1, gy1, gx2, gy2, areag);
            float ec = INF_F;
            if (p2.w != 0.0f) ec = cost_exact(p2, gcx, gcy, scores[(size_t)i * NCLS + lab], iou);
            u64 k2 = (((u64)__float_as_uint(ec)) << 32) | (unsigned)i;
            if (k2 < lf[KTOP - 1]) {
                lf[KTOP - 1] = k2;
                #pragma unroll
                for (int s = KTOP - 1; s > 0; --s)
                    if (lf[s] < lf[s - 1]) { u64 t = lf[s]; lf[s] = lf[s - 1]; lf[s - 1] = t; }
            }
        }
        wave_merge_minN<KTOP>(lf, &wco[wid * KTOP], lane);
        __syncthreads();
        if (wid == 0) {
            int p = 0;
            for (int r = 0; r < KTOP; ++r) {
                u64 cur = (lane < NW && p < KTOP) ? wco[lane * KTOP + p] : ~0ull;
                u64 bm = wave_min_bc_u64(cur);
                if (cur == bm && bm != ~0ull) p++;
                if (lane == 0) csel[r] = bm;
            }
        }
        __syncthreads();
    }

    // ---- finalize: ks from descending iou sum; scatter selections ----
    __syncthreads();
    if (wid == 0) {
        float tsum = 0.0f;
        #pragma unroll
        for (int r = 0; r < KTOP; ++r) {
            float v = s_iou13[r];
            tsum += (v == NEGINF) ? 0.0f : v;   // descending-order sum (missing = 0, as ref)
        }
        int ks = (int)tsum;
        if (ks < 1) ks = 1;
        if (lane < KTOP && lane < ks) {
            u64 mine = csel[lane];
            if (mine != ~0ull) {
                int idx = (int)(unsigned)(mine & 0xFFFFFFFFull);
                atomicAdd(&count[idx], 1);
                atomicMin(&firstgt[idx], j);
            }
        }
    }
}

// ---------- per-prior finalize; multi-matched priors resolved in-block ----------
__global__ __launch_bounds__(256) void k_assign(
        const float* __restrict__ scores,
        const float4* __restrict__ pbp, const float* __restrict__ gt,
        const void* labels, const int* flag,
        const int* __restrict__ count, const int* __restrict__ firstgt,
        float* __restrict__ out) {
    __shared__ float4 gbox[NGT];
    __shared__ int glab[NGT];
    __shared__ float gcxs[NGT], gcys[NGT], gareas[NGT];
    __shared__ int s_nm;
    __shared__ int s_mlist[256];
    __shared__ u64 red4[4];
    const int tid = threadIdx.x;
    const int is64 = *flag;
    {
        float4 b = ((const float4*)gt)[tid];
        gbox[tid] = b;
        glab[tid] = get_label(labels, tid, is64);
        gcxs[tid] = (b.x + b.z) * 0.5f;
        gcys[tid] = (b.y + b.w) * 0.5f;
        gareas[tid] = (b.z - b.x) * (b.w - b.y);
    }
    if (tid == 0) s_nm = 0;
    __syncthreads();
    const int i = blockIdx.x * 256 + tid;
    const bool act = (i < NPRI);
    if (act) {
        float4 p2 = pbp[2 * i + 1];
        int v = (p2.w != 0.0f) ? 1 : 0;
        int c = count[i];
        float o0 = 0.0f, o1 = -INF_F, o2 = -1.0f;
        if (v && c == 1) {
            int j = firstgt[i];
            float4 pb = pbp[2 * i];
            float areap = (pb.z - pb.x) * (pb.w - pb.y);
            float4 g = gbox[j];
            float iw = fmaxf(fminf(pb.z, g.z) - fmaxf(pb.x, g.x), 0.0f);
            float ih = fmaxf(fminf(pb.w, g.w) - fmaxf(pb.y, g.y), 0.0f);
            float inter = iw * ih;
            float iou = inter / fmaxf(areap + gareas[j] - inter, 1e-6f);
            o0 = (float)(j + 1); o1 = iou; o2 = (float)glab[j];
        } else if (v && c > 1) {
            int p = atomicAdd(&s_nm, 1);
            s_mlist[p] = i;
        }
        out[i] = o0;
        out[NPRI + i] = o1;
        out[2 * NPRI + i] = o2;
    }
    __syncthreads();
    // ---- in-block multi resolution: one GT per thread, block argmin per prior ----
    const int nm = s_nm;
    const int j = tid;
    for (int m = 0; m < nm; ++m) {
        const int ii = s_mlist[m];
        float4 pb = pbp[2 * ii];
        float4 p2 = pbp[2 * ii + 1];
        float areap = (pb.z - pb.x) * (pb.w - pb.y);

        float4 g = gbox[j];
        float iw = fmaxf(fminf(pb.z, g.z) - fmaxf(pb.x, g.x), 0.0f);
        float ih = fmaxf(fminf(pb.w, g.w) - fmaxf(pb.y, g.y), 0.0f);
        float inter = iw * ih;
        float iou = inter / fmaxf(areap + gareas[j] - inter, 1e-6f);
        float dx = p2.x - gcxs[j], dy = p2.y - gcys[j];
        float dist = sqrtf(dx * dx + dy * dy) / p2.z;
        float soft = exp2f((dist - 3.0f) * L10);
        float l = scores[(size_t)ii * NCLS + glab[j]];
        float sig = 1.0f / (1.0f + expf(-l));
        float dd = iou - sig;
        float bce = fmaxf(l, 0.0f) - l * iou + log1pf(expf(-fabsf(l)));
        float cost = bce * (dd * dd) + (-logf(iou + EPS_F) * 3.0f) + soft;

        u64 key = (((u64)__float_as_uint(cost)) << 32) | (unsigned)j;
        u64 v = key;
        #pragma unroll
        for (int off = 32; off > 0; off >>= 1) {
            u64 o = __shfl_down(v, off, 64);
            v = (o < v) ? o : v;
        }
        if ((tid & 63) == 0) red4[tid >> 6] = v;
        __syncthreads();
        u64 best = red4[0];
        #pragma unroll
        for (int q = 1; q < 4; ++q) best = (red4[q] < best) ? red4[q] : best;
        if (key == best) {
            out[ii] = (float)(j + 1);
            out[NPRI + ii] = iou;
            out[2 * NPRI + ii] = (float)glab[j];
        }
        __syncthreads();
    }
}

extern "C" void kernel_launch(void* const* d_in, const int* in_sizes, int n_in,
                              void* d_out, int out_size, void* d_ws, size_t ws_size,
                              hipStream_t stream) {
    const float* scores = (const float*)d_in[0];
    const float* priors = (const float*)d_in[1];
    const float* pboxes = (const float*)d_in[2];
    const float* gt     = (const float*)d_in[3];
    const void*  labels = d_in[4];
    float* out = (float*)d_out;

    char* ws = (char*)d_ws;
    size_t off = 0;
    auto alloc = [&](size_t bytes) { size_t o = off; off = (off + bytes + 255) & ~(size_t)255; return o; };
    int*    flag     = (int*)(ws + alloc(4));
    int*    count    = (int*)(ws + alloc((size_t)NPRI * 4));
    int*    firstgt  = (int*)(ws + alloc((size_t)NPRI * 4));
    float4* pbp      = (float4*)(ws + alloc((size_t)NPRI * 32));
    (void)ws_size;

    hipLaunchKernelGGL(k_prep, dim3(PREP_BLKS), dim3(256), 0, stream,
                       priors, gt, labels, pboxes, pbp, count, firstgt, flag);
    hipLaunchKernelGGL(k_scan, dim3(NGT), dim3(SCN_T), 0, stream,
                       scores, pbp, gt, labels, flag, count, firstgt);
    hipLaunchKernelGGL(k_assign, dim3((NPRI + 255) / 256), dim3(256), 0, stream,
                       scores, pbp, gt, labels, flag, count, firstgt, out);
}